// Round 3
// baseline (54.572 us; speedup 1.0000x reference)
//
#include <hip/hip_runtime.h>
#include <hip/hip_bf16.h>
#include <math.h>

// BayesianSkipgram: V=100000, E=256, D=128, B=8192, C=10
// v3: 512-thread blocks (8 waves, 2 blocks/CU = 50% occupancy),
//     weights register-resident (M_w frags loaded once; U_w/W_w frags
//     loaded once before phase 2), double-buffered gathered-A staging
//     (one barrier per K-chunk, loads in flight across barriers).

#define BT    16
#define SLOTS 11
#define ROWS  176          // r = c*16 + b (slot-major)
#define EDIM  256
#define DDIM  128
#define CTXN  10
#define EK    64
#define LP    72           // A row stride (ushorts): 144B = 16*9 -> b128-aligned, 2-way bank alias (free)
#define HLP   264          // h row stride: 528B = 16*33
#define ACH   (ROWS*LP)    // 12672 ushorts per A buffer

typedef short  bf16x8 __attribute__((ext_vector_type(8)));
typedef float  f32x4  __attribute__((ext_vector_type(4)));

__device__ __forceinline__ uint2 cvt4(float4 v) {
    union { __hip_bfloat162 h2; unsigned u; } a, b;
    a.h2 = __float22bfloat162_rn(make_float2(v.x, v.y));
    b.h2 = __float22bfloat162_rn(make_float2(v.z, v.w));
    return make_uint2(a.u, b.u);
}

__device__ __forceinline__ bf16x8 cvt8(float4 a, float4 b) {
    union { __hip_bfloat162 h2[4]; bf16x8 v; } u;
    u.h2[0] = __float22bfloat162_rn(make_float2(a.x, a.y));
    u.h2[1] = __float22bfloat162_rn(make_float2(a.z, a.w));
    u.h2[2] = __float22bfloat162_rn(make_float2(b.x, b.y));
    u.h2[3] = __float22bfloat162_rn(make_float2(b.z, b.w));
    return u.v;
}

__device__ __forceinline__ float softplusf(float v) {
    return fmaxf(v, 0.0f) + log1pf(expf(-fabsf(v)));
}

__device__ __forceinline__ void load_A(const float* __restrict__ W_emb,
                                       const int* idx_s, int k0, int tid,
                                       float4* sreg) {
#pragma unroll
    for (int s = 0; s < 6; ++s) {
        int it = tid + 512 * s;
        if (it < ROWS * 16) {
            int r = it >> 4, q = it & 15;
            sreg[s] = ((const float4*)W_emb)[(size_t)idx_s[r] * 64 + (k0 >> 2) + q];
        }
    }
}

__device__ __forceinline__ void write_A(unsigned short* A, int tid,
                                        const float4* sreg) {
#pragma unroll
    for (int s = 0; s < 6; ++s) {
        int it = tid + 512 * s;
        if (it < ROWS * 16) {
            int r = it >> 4, q = it & 15;
            *(uint2*)&A[r * LP + 4 * q] = cvt4(sreg[s]);
        }
    }
}

__global__ __launch_bounds__(512, 4) void bsg_v3(
    const int*   __restrict__ x,     const int*   __restrict__ ctx,
    const float* __restrict__ W_emb, const float* __restrict__ M_w,
    const float* __restrict__ M_b,   const float* __restrict__ U_w,
    const float* __restrict__ U_b,   const float* __restrict__ W_w,
    const float* __restrict__ W_b,   const float* __restrict__ pmu,
    const float* __restrict__ psg,   float* __restrict__ out)
{
    __shared__ unsigned short A_s[2 * ACH];   // 50688 B
    __shared__ unsigned short H_s[16 * HLP];  // 8448 B
    __shared__ int   idx_s[ROWS];
    __shared__ float P_s[BT * 8];

    const int tid  = threadIdx.x;
    const int b0   = blockIdx.x * BT;
    const int w    = tid >> 6;        // wave 0..7; owns N-tile w (cols 16w..16w+15)
    const int lane = tid & 63;
    const int l15  = lane & 15;
    const int lg   = lane >> 4;

    // ---- M_w B-fragments -> registers (issued first; no idx dependency) ----
    const int mrow = 16 * w + l15;
    bf16x8 mreg[8];
#pragma unroll
    for (int kk = 0; kk < 8; ++kk) {
        float4 a = ((const float4*)M_w)[mrow * 64 + 8 * kk + 2 * lg];
        float4 b = ((const float4*)M_w)[mrow * 64 + 8 * kk + 2 * lg + 1];
        mreg[kk] = cvt8(a, b);
    }

    if (tid < ROWS) {
        int c = tid >> 4, b = b0 + (tid & 15);
        idx_s[tid] = (c == 0) ? x[b] : ctx[b * CTXN + (c - 1)];
    }
    __syncthreads();

    // ---------------- phase 1: Rall = gathered_emb @ M_w^T ----------------
    float4 sreg[6];
    load_A(W_emb, idx_s, 0, tid, sreg);
    write_A(A_s, tid, sreg);

    f32x4 acc[SLOTS] = {};
#pragma unroll
    for (int ch = 0; ch < 4; ++ch) {
        if (ch < 3) load_A(W_emb, idx_s, (ch + 1) * EK, tid, sreg);  // issue early
        __syncthreads();                       // buf[ch&1] visible; buf[(ch-1)&1] free
        const unsigned short* Ab = A_s + (ch & 1) * ACH;
#pragma unroll
        for (int c = 0; c < SLOTS; ++c) {
            bf16x8 a0 = *(const bf16x8*)&Ab[(16 * c + l15) * LP + 8 * lg];
            bf16x8 a1 = *(const bf16x8*)&Ab[(16 * c + l15) * LP + 32 + 8 * lg];
            acc[c] = __builtin_amdgcn_mfma_f32_16x16x32_bf16(a0, mreg[2 * ch],     acc[c], 0, 0, 0);
            acc[c] = __builtin_amdgcn_mfma_f32_16x16x32_bf16(a1, mreg[2 * ch + 1], acc[c], 0, 0, 0);
        }
        if (ch < 3) write_A(A_s + ((ch + 1) & 1) * ACH, tid, sreg);  // other buffer
    }

    // ---- relu-sum -> h (bf16, LDS); acc dies here ----
    {
        const int dg = 16 * w + l15;
        const float mb = M_b[dg];
#pragma unroll
        for (int q = 0; q < 4; ++q) {
            int m = lg * 4 + q;
            float h1 = 10.0f * fmaxf(acc[0][q] + mb, 0.0f);
            float h2 = 0.0f;
#pragma unroll
            for (int c = 1; c < SLOTS; ++c) h2 += fmaxf(acc[c][q] + mb, 0.0f);
            __hip_bfloat16 t1 = __float2bfloat16(h1);
            __hip_bfloat16 t2 = __float2bfloat16(h2);
            H_s[m * HLP + dg]       = *(unsigned short*)&t1;
            H_s[m * HLP + 128 + dg] = *(unsigned short*)&t2;
        }
    }

    // ---- prior gathers + U/W B-fragments (issued before barrier; hidden) ----
    float pm[4], ps[4];
#pragma unroll
    for (int q = 0; q < 4; ++q) {
        int xb = idx_s[lg * 4 + q];            // x[b0 + m] (slot-0 rows)
        pm[q] = pmu[(size_t)xb * DDIM + 16 * w + l15];
        ps[q] = psg[(size_t)xb * DDIM + 16 * w + l15];
    }
    const int urow = 16 * w + l15;
    bf16x8 ufrag[8], wfrag[8];
#pragma unroll
    for (int kk = 0; kk < 8; ++kk) {
        float4 a = ((const float4*)U_w)[urow * 64 + 8 * kk + 2 * lg];
        float4 b = ((const float4*)U_w)[urow * 64 + 8 * kk + 2 * lg + 1];
        ufrag[kk] = cvt8(a, b);
    }
#pragma unroll
    for (int kk = 0; kk < 8; ++kk) {
        float4 a = ((const float4*)W_w)[urow * 64 + 8 * kk + 2 * lg];
        float4 b = ((const float4*)W_w)[urow * 64 + 8 * kk + 2 * lg + 1];
        wfrag[kk] = cvt8(a, b);
    }
    __syncthreads();   // H_s visible

    // ---------------- phase 2: [mu|presig] = h @ [U_w;W_w]^T ----------------
    f32x4 acc2[2] = {};
    bf16x8 haf[8];
#pragma unroll
    for (int kk = 0; kk < 8; ++kk)
        haf[kk] = *(const bf16x8*)&H_s[l15 * HLP + 32 * kk + 8 * lg];
#pragma unroll
    for (int kk = 0; kk < 8; ++kk) {
        acc2[0] = __builtin_amdgcn_mfma_f32_16x16x32_bf16(haf[kk], ufrag[kk], acc2[0], 0, 0, 0);
        acc2[1] = __builtin_amdgcn_mfma_f32_16x16x32_bf16(haf[kk], wfrag[kk], acc2[1], 0, 0, 0);
    }

    // ---------------- epilogue: bias, softplus, KL ----------------
    const float ub = U_b[16 * w + l15];
    const float wb = W_b[16 * w + l15];
#pragma unroll
    for (int q = 0; q < 4; ++q) {
        float mu = acc2[0][q] + ub;
        float sg = softplusf(acc2[1][q] + wb);
        float dm = mu - pm[q];
        float p  = ps[q] / sg + dm * dm / sg + logf(sg) - logf(ps[q]);
        p += __shfl_xor(p, 1);
        p += __shfl_xor(p, 2);
        p += __shfl_xor(p, 4);
        p += __shfl_xor(p, 8);
        if (l15 == 0) P_s[(lg * 4 + q) * 8 + w] = p;
    }
    __syncthreads();
    if (tid < BT) {
        float s = 0.0f;
#pragma unroll
        for (int k = 0; k < 8; ++k) s += P_s[tid * 8 + k];
        out[b0 + tid] = 0.5f * (s - (float)DDIM);
    }
}

extern "C" void kernel_launch(void* const* d_in, const int* in_sizes, int n_in,
                              void* d_out, int out_size, void* d_ws, size_t ws_size,
                              hipStream_t stream) {
    const int*   x     = (const int*)  d_in[0];
    const int*   ctx   = (const int*)  d_in[1];
    const float* W_emb = (const float*)d_in[2];
    const float* M_w   = (const float*)d_in[3];
    const float* M_b   = (const float*)d_in[4];
    const float* U_w   = (const float*)d_in[5];
    const float* U_b   = (const float*)d_in[6];
    const float* W_w   = (const float*)d_in[7];
    const float* W_b   = (const float*)d_in[8];
    const float* pmu   = (const float*)d_in[9];
    const float* psg   = (const float*)d_in[10];
    float* out = (float*)d_out;

    bsg_v3<<<dim3(8192 / BT), dim3(512), 0, stream>>>(
        x, ctx, W_emb, M_w, M_b, U_w, U_b, W_w, W_b, pmu, psg, out);
}

// Round 4
// 44.602 us; speedup vs baseline: 1.2235x; 1.2235x over previous
//
#include <hip/hip_runtime.h>
#include <hip/hip_bf16.h>
#include <math.h>

// BayesianSkipgram: V=100000, E=256, D=128, B=8192, C=10
// v4: three-kernel split.
//   k_cvt : M_w/U_w/W_w fp32 -> bf16 into ws (192 KB, done every call)
//   bsg_h : gathered-GEMM + relu-sum -> h[8192,256] bf16 in ws
//           (BT=8, 512 thr, 1024 blocks -> 4 blocks/CU; acc[6]+chunked mreg
//            keeps live regs ~65 -> no spills, unlike v3)
//   bsg_kl: h @ [U;W]^T + softplus + prior gather + KL -> out
//
// ws layout (ushort units): M_bf [0,32768), U_bf [32768,65536),
// W_bf [65536,98304) (U,W contiguous => one [256][256] array), h [98304, +8192*256)
// total = 4,390,912 bytes required.

#define CTXN  10
#define EDIM  256
#define DDIM  128
#define WS_M   0
#define WS_UW  32768
#define WS_H   98304

typedef short bf16x8 __attribute__((ext_vector_type(8)));
typedef float f32x4  __attribute__((ext_vector_type(4)));

__device__ __forceinline__ uint2 cvt4(float4 v) {
    union { __hip_bfloat162 h2; unsigned u; } a, b;
    a.h2 = __float22bfloat162_rn(make_float2(v.x, v.y));
    b.h2 = __float22bfloat162_rn(make_float2(v.z, v.w));
    return make_uint2(a.u, b.u);
}

__device__ __forceinline__ float softplusf(float v) {
    return fmaxf(v, 0.0f) + log1pf(expf(-fabsf(v)));
}

// ---------------- kernel 0: weight fp32 -> bf16 ----------------
__global__ __launch_bounds__(256) void k_cvt(
    const float* __restrict__ M_w, const float* __restrict__ U_w,
    const float* __restrict__ W_w, unsigned short* __restrict__ ws)
{
    int which = blockIdx.x >> 5;                       // 0:M 1:U 2:W
    int i = ((blockIdx.x & 31) << 8) | threadIdx.x;    // float4 idx 0..8191
    const float* src = (which == 0) ? M_w : (which == 1) ? U_w : W_w;
    float4 v = ((const float4*)src)[i];
    *(uint2*)&ws[which * 32768 + i * 4] = cvt4(v);
}

// ---------------- kernel 1: gather + emb@M_w^T + relu-sum -> h ----------------
#define BT1   8
#define ROWS1 88              // r = c*8 + b, c=0..10
#define LP    72              // LDS row stride (ushort): 144B, 2-way bank alias (free)
#define ACH   (96 * LP)       // alloc 96 rows (rows 88..95 read-garbage, ignored)

__device__ __forceinline__ void load_A8(const float* __restrict__ W_emb,
                                        const int* idx_s, int k0f4, int tid,
                                        float4* sreg) {
#pragma unroll
    for (int s = 0; s < 3; ++s) {
        int it = tid + 512 * s;
        if (it < ROWS1 * 16) {
            int r = it >> 4, q = it & 15;
            sreg[s] = ((const float4*)W_emb)[(size_t)idx_s[r] * 64 + k0f4 + q];
        }
    }
}
__device__ __forceinline__ void write_A8(unsigned short* A, int tid,
                                         const float4* sreg) {
#pragma unroll
    for (int s = 0; s < 3; ++s) {
        int it = tid + 512 * s;
        if (it < ROWS1 * 16) {
            int r = it >> 4, q = it & 15;
            *(uint2*)&A[r * LP + 4 * q] = cvt4(sreg[s]);
        }
    }
}

__global__ __launch_bounds__(512, 4) void bsg_h(
    const int* __restrict__ x, const int* __restrict__ ctx,
    const float* __restrict__ W_emb, const float* __restrict__ M_b,
    const unsigned short* __restrict__ wsr, unsigned short* __restrict__ hws)
{
    __shared__ unsigned short A_s[2 * ACH];   // 27648 B
    __shared__ int idx_s[ROWS1];

    const int tid  = threadIdx.x;
    const int b0   = blockIdx.x * BT1;
    const int w    = tid >> 6;       // wave 0..7 owns cols 16w..16w+15
    const int lane = tid & 63;
    const int l15  = lane & 15;
    const int lg   = lane >> 4;

    if (tid < ROWS1) {
        int c = tid >> 3, b = b0 + (tid & 7);
        idx_s[tid] = (c == 0) ? x[b] : ctx[b * CTXN + (c - 1)];
    }
    __syncthreads();

    float4 sreg[3];
    load_A8(W_emb, idx_s, 0, tid, sreg);
    write_A8(A_s, tid, sreg);

    const unsigned short* Mb_bf = wsr + WS_M;   // [128][256] bf16
    const int mrow = 16 * w + l15;
    f32x4 acc[6] = {};

#pragma unroll
    for (int ch = 0; ch < 4; ++ch) {
        if (ch < 3) load_A8(W_emb, idx_s, (ch + 1) * 16, tid, sreg);  // issue early
        __syncthreads();
        bf16x8 m0 = *(const bf16x8*)&Mb_bf[mrow * 256 + 64 * ch + 8 * lg];
        bf16x8 m1 = *(const bf16x8*)&Mb_bf[mrow * 256 + 64 * ch + 32 + 8 * lg];
        const unsigned short* Ab = A_s + (ch & 1) * ACH;
#pragma unroll
        for (int mt = 0; mt < 6; ++mt) {
            bf16x8 a0 = *(const bf16x8*)&Ab[(16 * mt + l15) * LP + 8 * lg];
            bf16x8 a1 = *(const bf16x8*)&Ab[(16 * mt + l15) * LP + 32 + 8 * lg];
            acc[mt] = __builtin_amdgcn_mfma_f32_16x16x32_bf16(a0, m0, acc[mt], 0, 0, 0);
            acc[mt] = __builtin_amdgcn_mfma_f32_16x16x32_bf16(a1, m1, acc[mt], 0, 0, 0);
        }
        if (ch < 3) write_A8(A_s + ((ch + 1) & 1) * ACH, tid, sreg);   // write late
    }

    // relu-sum: lane holds rows 16mt+4lg+q; c = row>>3, b = row&7.
    // lg<2 -> even slots (c=2mt), lg>=2 -> odd slots (c=2mt+1); b = (4lg+q)&7.
    const int dg = 16 * w + l15;
    const float mb = M_b[dg];
    float p1[4] = {0, 0, 0, 0}, p2[4] = {0, 0, 0, 0};
#pragma unroll
    for (int mt = 0; mt < 6; ++mt) {
#pragma unroll
        for (int q = 0; q < 4; ++q) {
            float r = fmaxf(acc[mt][q] + mb, 0.0f);
            if (lg < 2) { if (mt == 0) p1[q] = r; else p2[q] += r; }   // slots 0,2,4,6,8,10
            else        { if (mt < 5)  p2[q] += r; }                   // slots 1,3,5,7,9 (11=pad)
        }
    }
#pragma unroll
    for (int q = 0; q < 4; ++q) {
        float other = __shfl_xor(p2[q], 32);     // pair lg0<->lg2, lg1<->lg3
        if (lg < 2) {
            int b = 4 * lg + q;
            __hip_bfloat16 t1 = __float2bfloat16(10.0f * p1[q]);     // C * relu(Rw)
            __hip_bfloat16 t2 = __float2bfloat16(p2[q] + other);     // sum_c relu(Rc)
            hws[(size_t)(b0 + b) * 256 + dg]       = *(unsigned short*)&t1;
            hws[(size_t)(b0 + b) * 256 + 128 + dg] = *(unsigned short*)&t2;
        }
    }
}

// ---------------- kernel 2: h @ [U;W]^T + softplus + KL ----------------
#define BT2  32
#define HLP  264

__global__ __launch_bounds__(512, 4) void bsg_kl(
    const int* __restrict__ x, const float* __restrict__ U_b,
    const float* __restrict__ W_b, const float* __restrict__ pmu,
    const float* __restrict__ psg, const unsigned short* __restrict__ wsr,
    float* __restrict__ out)
{
    __shared__ unsigned short H_s[BT2 * HLP];   // 16896 B
    __shared__ int   xs[BT2];
    __shared__ float P_s[BT2 * 8];

    const int tid  = threadIdx.x;
    const int b0   = blockIdx.x * BT2;
    const int w    = tid >> 6;       // wave 0..7 owns d-cols 16w..16w+15 (mu + presig)
    const int lane = tid & 63;
    const int l15  = lane & 15;
    const int lg   = lane >> 4;

    if (tid < BT2) xs[tid] = x[b0 + tid];
    const unsigned short* hws = wsr + WS_H;
#pragma unroll
    for (int s = 0; s < 2; ++s) {                // 1024 x 16B copies
        int it = tid + 512 * s;
        int r = it >> 5, q = it & 31;
        *(uint4*)&H_s[r * HLP + 8 * q] =
            *(const uint4*)&hws[(size_t)(b0 + r) * 256 + 8 * q];
    }
    __syncthreads();

    const unsigned short* UWb = wsr + WS_UW;     // [256][256] bf16, rows: 0..127=U, 128..255=W
    const int nrow = 16 * w + l15;
    f32x4 acc2[2][2] = {};                       // [mtile][0=mu,1=presig]
#pragma unroll
    for (int ks = 0; ks < 8; ++ks) {
        bf16x8 bu = *(const bf16x8*)&UWb[nrow * 256 + 32 * ks + 8 * lg];
        bf16x8 bw = *(const bf16x8*)&UWb[(128 + nrow) * 256 + 32 * ks + 8 * lg];
#pragma unroll
        for (int mt = 0; mt < 2; ++mt) {
            bf16x8 hf = *(const bf16x8*)&H_s[(16 * mt + l15) * HLP + 32 * ks + 8 * lg];
            acc2[mt][0] = __builtin_amdgcn_mfma_f32_16x16x32_bf16(hf, bu, acc2[mt][0], 0, 0, 0);
            acc2[mt][1] = __builtin_amdgcn_mfma_f32_16x16x32_bf16(hf, bw, acc2[mt][1], 0, 0, 0);
        }
    }

    const int d = 16 * w + l15;
    const float ub = U_b[d], wb = W_b[d];
#pragma unroll
    for (int mt = 0; mt < 2; ++mt) {
#pragma unroll
        for (int q = 0; q < 4; ++q) {
            int rb = 16 * mt + 4 * lg + q;
            int xb = xs[rb];
            float mu = acc2[mt][0][q] + ub;
            float sg = softplusf(acc2[mt][1][q] + wb);
            float m0 = pmu[(size_t)xb * DDIM + d];
            float s0 = psg[(size_t)xb * DDIM + d];
            float dm = mu - m0;
            float p  = s0 / sg + dm * dm / sg + logf(sg) - logf(s0);
            p += __shfl_xor(p, 1);
            p += __shfl_xor(p, 2);
            p += __shfl_xor(p, 4);
            p += __shfl_xor(p, 8);
            if (l15 == 0) P_s[rb * 8 + w] = p;
        }
    }
    __syncthreads();
    if (tid < BT2) {
        float s = 0.0f;
#pragma unroll
        for (int k = 0; k < 8; ++k) s += P_s[tid * 8 + k];
        out[b0 + tid] = 0.5f * (s - (float)DDIM);
    }
}

extern "C" void kernel_launch(void* const* d_in, const int* in_sizes, int n_in,
                              void* d_out, int out_size, void* d_ws, size_t ws_size,
                              hipStream_t stream) {
    const int*   x     = (const int*)  d_in[0];
    const int*   ctx   = (const int*)  d_in[1];
    const float* W_emb = (const float*)d_in[2];
    const float* M_w   = (const float*)d_in[3];
    const float* M_b   = (const float*)d_in[4];
    const float* U_w   = (const float*)d_in[5];
    const float* U_b   = (const float*)d_in[6];
    const float* W_w   = (const float*)d_in[7];
    const float* W_b   = (const float*)d_in[8];
    const float* pmu   = (const float*)d_in[9];
    const float* psg   = (const float*)d_in[10];
    float* out = (float*)d_out;
    unsigned short* ws = (unsigned short*)d_ws;   // needs >= 4,390,912 bytes

    k_cvt<<<dim3(96), dim3(256), 0, stream>>>(M_w, U_w, W_w, ws);
    bsg_h<<<dim3(8192 / BT1), dim3(512), 0, stream>>>(x, ctx, W_emb, M_b,
                                                      ws, ws + WS_H);
    bsg_kl<<<dim3(8192 / BT2), dim3(512), 0, stream>>>(x, U_b, W_b, pmu, psg,
                                                       ws, out);
}